// Round 10
// baseline (69.191 us; speedup 1.0000x reference)
//
#include <hip/hip_runtime.h>
#include <hip/hip_bf16.h>

#define NHALF 4096
#define TWO_N 8192
#define DDIM 256
#define INV_T 10.0f
// 10 * log2(e): exp(10*s) = exp2(s * SCALE) where s is the raw cosine dot
#define SCALE 14.426950408889634f

typedef __bf16 v8bf __attribute__((ext_vector_type(8)));
typedef float f32x4 __attribute__((ext_vector_type(4)));

#define AS1 __attribute__((address_space(1)))
#define AS3 __attribute__((address_space(3)))

#if __has_builtin(__builtin_amdgcn_exp2f)
#define EXP2F(x) __builtin_amdgcn_exp2f(x)
#else
#define EXP2F(x) exp2f(x)
#endif

static __device__ __forceinline__ unsigned short f2bf(float x) {
    __hip_bfloat16 h = __float2bfloat16(x);
    return *(unsigned short*)&h;
}

// ---------------- kernel 1: normalize rows -> bf16 zn; zero rowacc & out ----
__global__ __launch_bounds__(256) void ntx_norm_kernel(
    const float* __restrict__ zi, const float* __restrict__ zj,
    __hip_bfloat16* __restrict__ zn, float* __restrict__ rowacc,
    float* __restrict__ out) {
    const int w = threadIdx.x >> 6;
    const int lane = threadIdx.x & 63;
    const int r = blockIdx.x * 4 + w;
    const float* src = (r < NHALF) ? (zi + (size_t)r * DDIM)
                                   : (zj + (size_t)(r - NHALF) * DDIM);
    float4 v = ((const float4*)src)[lane];
    float ss = v.x * v.x + v.y * v.y + v.z * v.z + v.w * v.w;
#pragma unroll
    for (int m = 1; m < 64; m <<= 1) ss += __shfl_xor(ss, m);
    float rinv = 1.0f / fmaxf(sqrtf(ss), 1e-8f);
    ushort4 o;
    o.x = f2bf(v.x * rinv);
    o.y = f2bf(v.y * rinv);
    o.z = f2bf(v.z * rinv);
    o.w = f2bf(v.w * rinv);
    ((ushort4*)(zn + (size_t)r * DDIM))[lane] = o;
    if (blockIdx.x < 32) rowacc[blockIdx.x * 256 + threadIdx.x] = 0.0f;
    if (blockIdx.x == 0 && threadIdx.x == 0) out[0] = 0.0f;
}

// ---------------- kernel 2: symmetric Gram + exp sums (m97 structure) -------
// 64 row-groups of 128; triangle pairs I>=J: 2080 blocks, 2/CU -> 4.06 rounds.
// Block = S[I:128][J:128], K=256 in 4 steps of BK=64. 4 waves in 2x2; wave
// computes 64x64 = 4x4 fragments of 16x16, acc (64 VGPR) is the ONLY state
// living across the K-loop (R3-R9 failure: pinned-A sets lost to allocator
// sink/spill). Staging: width-16 global_load_lds direct to LDS, linear dest,
// PRE-SWIZZLED global source (slot ^= row&7); ds_read applies the same XOR
// (rule #21 involution) -> conflict-free b128 fragment reads.
// Double-buffered 2x(16+16)KB = 64KB LDS. Epilogue once per block from acc:
// row-sums -> rowacc[I rows]; col-sums (mirror, symmetry) -> rowacc[J rows];
// positives on local diag of I-J==32 blocks; self-diag masked when I==J.
__global__ __launch_bounds__(256, 2) void ntx_gram_kernel(
    const __hip_bfloat16* __restrict__ zn,
    float* __restrict__ rowacc,    // [TWO_N] atomic accumulation
    float* __restrict__ spos) {    // [TWO_N]
    // triangle decode over 64 groups
    const int b = blockIdx.x;
    int I = (int)((sqrtf(8.0f * b + 1.0f) - 1.0f) * 0.5f);
    while ((I + 1) * (I + 2) / 2 <= b) ++I;
    while (I * (I + 1) / 2 > b) --I;
    const int J = b - I * (I + 1) / 2;
    const bool sameIJ = (I == J);
    const bool posblk = (I - J) == 32;
    const int Ibase = I * 128, Jbase = J * 128;

    const int tid = threadIdx.x;
    const int w = tid >> 6, lane = tid & 63;
    const int wr = w >> 1, wc = w & 1;     // wave's 2x2 position
    const int lrow = lane & 15, lk = lane >> 4;

    const char* znb = (const char*)zn;     // zn row stride = 512 B

    __shared__ char lds[65536];            // buf k: A @ k*32768, B @ +16384

    // staging geometry: 1 gload_lds = 1KB = 8 rows x 128B; lane -> (row, slot)
    const int sr = lane >> 3;              // row within 8-row slab
    const int ss = lane & 7;               // 16B slot within row

#define STAGE(buf, kk)                                                        \
    do {                                                                      \
        _Pragma("unroll")                                                     \
        for (int p = 0; p < 4; ++p) {                                         \
            const int rb = w * 32 + p * 8;                                    \
            const int rr = rb + sr;                                           \
            const int so = ((ss ^ (rr & 7)) << 4);                            \
            const char* ga =                                                  \
                znb + (size_t)(Ibase + rr) * 512 + (kk) * 128 + so;           \
            const char* gb =                                                  \
                znb + (size_t)(Jbase + rr) * 512 + (kk) * 128 + so;           \
            __builtin_amdgcn_global_load_lds(                                 \
                (const AS1 void*)ga,                                          \
                (AS3 void*)(lds + (buf) * 32768 + rb * 128), 16, 0, 0);       \
            __builtin_amdgcn_global_load_lds(                                 \
                (const AS1 void*)gb,                                          \
                (AS3 void*)(lds + (buf) * 32768 + 16384 + rb * 128), 16, 0,   \
                0);                                                           \
        }                                                                     \
    } while (0)

#define COMPUTE(buf)                                                          \
    do {                                                                      \
        f32x4 a[4][2], bbf[4][2];                                             \
        _Pragma("unroll")                                                     \
        for (int rf = 0; rf < 4; ++rf) {                                      \
            const int r = wr * 64 + rf * 16 + lrow;                           \
            _Pragma("unroll")                                                 \
            for (int kb = 0; kb < 2; ++kb)                                    \
                a[rf][kb] = *(const f32x4*)(lds + (buf) * 32768 + r * 128 +   \
                                            (((kb * 4 + lk) ^ (r & 7)) << 4));\
        }                                                                     \
        _Pragma("unroll")                                                     \
        for (int cf = 0; cf < 4; ++cf) {                                      \
            const int c = wc * 64 + cf * 16 + lrow;                           \
            _Pragma("unroll")                                                 \
            for (int kb = 0; kb < 2; ++kb)                                    \
                bbf[cf][kb] =                                                 \
                    *(const f32x4*)(lds + (buf) * 32768 + 16384 + c * 128 +   \
                                    (((kb * 4 + lk) ^ (c & 7)) << 4));        \
        }                                                                     \
        _Pragma("unroll")                                                     \
        for (int kb = 0; kb < 2; ++kb) {                                      \
            _Pragma("unroll")                                                 \
            for (int rf = 0; rf < 4; ++rf)                                    \
                _Pragma("unroll")                                             \
                for (int cf = 0; cf < 4; ++cf)                                \
                    acc[rf][cf] = __builtin_amdgcn_mfma_f32_16x16x32_bf16(    \
                        __builtin_bit_cast(v8bf, a[rf][kb]),                  \
                        __builtin_bit_cast(v8bf, bbf[cf][kb]), acc[rf][cf],   \
                        0, 0, 0);                                             \
        }                                                                     \
    } while (0)

    f32x4 acc[4][4];
#pragma unroll
    for (int rf = 0; rf < 4; ++rf)
#pragma unroll
        for (int cf = 0; cf < 4; ++cf) acc[rf][cf] = (f32x4){0.f, 0.f, 0.f, 0.f};

    STAGE(0, 0);
    __syncthreads();                        // buf0 staged (vmcnt drained)
#pragma unroll
    for (int k = 0; k < 4; ++k) {
        if (k < 3) STAGE((k + 1) & 1, k + 1);  // prefetch next K-step
        COMPUTE(k & 1);
        __syncthreads();                    // next buf staged + reads done
    }
#undef STAGE
#undef COMPUTE

    // ---------------- epilogue: exp, sums, spos, diag ----------------
    bool odg[4];
#pragma unroll
    for (int j = 0; j < 4; ++j) odg[j] = (lrow == lk * 4 + j);

    float rsum[4][4];
#pragma unroll
    for (int rf = 0; rf < 4; ++rf)
#pragma unroll
        for (int j = 0; j < 4; ++j) rsum[rf][j] = 0.0f;
    float csum[4] = {0.f, 0.f, 0.f, 0.f};

#pragma unroll
    for (int rf = 0; rf < 4; ++rf) {
#pragma unroll
        for (int cf = 0; cf < 4; ++cf) {
            const bool dfrag = (wr == wc) && (rf == cf);
#pragma unroll
            for (int j = 0; j < 4; ++j) {
                const float s = acc[rf][cf][j];
                const bool od = dfrag && odg[j];
                if (posblk && od) {
                    const int u = wr * 64 + rf * 16 + lk * 4 + j;
                    spos[Ibase + u] = s * INV_T;
                    spos[Jbase + u] = s * INV_T;
                }
                float e = EXP2F(s * SCALE);
                e = (sameIJ && od) ? 0.0f : e;
                rsum[rf][j] += e;
                csum[cf] += e;
            }
        }
    }

    // row-sums: reduce over the 16 col-lanes (bits 0..3 of lane)
#pragma unroll
    for (int rf = 0; rf < 4; ++rf) {
#pragma unroll
        for (int j = 0; j < 4; ++j) {
            float v = rsum[rf][j];
            v += __shfl_xor(v, 1);
            v += __shfl_xor(v, 2);
            v += __shfl_xor(v, 4);
            v += __shfl_xor(v, 8);
            if (lrow == 0)
                atomicAdd(&rowacc[Ibase + wr * 64 + rf * 16 + lk * 4 + j], v);
        }
    }
    // col-sums (mirror contribution): reduce over the 4 lk-groups
    if (!sameIJ) {
#pragma unroll
        for (int cf = 0; cf < 4; ++cf) {
            float v = csum[cf];
            v += __shfl_xor(v, 16);
            v += __shfl_xor(v, 32);
            if (lane < 16)
                atomicAdd(&rowacc[Jbase + wc * 64 + cf * 16 + lrow], v);
        }
    }
}

// ---------------- kernel 3: finalize ----------------
__global__ __launch_bounds__(256) void ntx_final_kernel(
    const float* __restrict__ rowacc, const float* __restrict__ spos,
    float* __restrict__ out) {
    const int tid = threadIdx.x;
    const int r = blockIdx.x * 256 + tid;
    float nll = logf(rowacc[r]) - spos[r];
    __shared__ float red[256];
    red[tid] = nll;
    __syncthreads();
    for (int s = 128; s > 0; s >>= 1) {
        if (tid < s) red[tid] += red[tid + s];
        __syncthreads();
    }
    if (tid == 0) atomicAdd(out, red[0] * (1.0f / (float)TWO_N));
}

extern "C" void kernel_launch(void* const* d_in, const int* in_sizes, int n_in,
                              void* d_out, int out_size, void* d_ws, size_t ws_size,
                              hipStream_t stream) {
    const float* zi = (const float*)d_in[0];
    const float* zj = (const float*)d_in[1];
    char* ws = (char*)d_ws;
    __hip_bfloat16* zn = (__hip_bfloat16*)ws;                          // 4 MB
    size_t off = (size_t)TWO_N * DDIM * 2;
    float* spos = (float*)(ws + off);                                  // 32 KB
    off += (size_t)TWO_N * 4;
    float* rowacc = (float*)(ws + off);                                // 32 KB
    float* out = (float*)d_out;

    ntx_norm_kernel<<<TWO_N / 4, 256, 0, stream>>>(zi, zj, zn, rowacc, out);
    ntx_gram_kernel<<<2080, 256, 0, stream>>>(zn, rowacc, spos);
    ntx_final_kernel<<<TWO_N / 256, 256, 0, stream>>>(rowacc, spos, out);
}

// Round 11
// 61.708 us; speedup vs baseline: 1.1213x; 1.1213x over previous
//
#include <hip/hip_runtime.h>
#include <hip/hip_bf16.h>

#define NHALF 4096
#define TWO_N 8192
#define DDIM 256
#define INV_T 10.0f
// 10 * log2(e): exp(10*s) = exp2(s * SCALE) where s is the raw cosine dot
#define SCALE 14.426950408889634f

typedef __bf16 v8bf __attribute__((ext_vector_type(8)));
typedef float f32x4 __attribute__((ext_vector_type(4)));

#define AS1 __attribute__((address_space(1)))
#define AS3 __attribute__((address_space(3)))

#if __has_builtin(__builtin_amdgcn_exp2f)
#define EXP2F(x) __builtin_amdgcn_exp2f(x)
#else
#define EXP2F(x) exp2f(x)
#endif

static __device__ __forceinline__ unsigned short f2bf(float x) {
    __hip_bfloat16 h = __float2bfloat16(x);
    return *(unsigned short*)&h;
}

// ---------------- kernel 1: normalize rows -> bf16 zn; zero rowacc & out ----
__global__ __launch_bounds__(256) void ntx_norm_kernel(
    const float* __restrict__ zi, const float* __restrict__ zj,
    __hip_bfloat16* __restrict__ zn, float* __restrict__ rowacc,
    float* __restrict__ out) {
    const int w = threadIdx.x >> 6;
    const int lane = threadIdx.x & 63;
    const int r = blockIdx.x * 4 + w;
    const float* src = (r < NHALF) ? (zi + (size_t)r * DDIM)
                                   : (zj + (size_t)(r - NHALF) * DDIM);
    float4 v = ((const float4*)src)[lane];
    float ss = v.x * v.x + v.y * v.y + v.z * v.z + v.w * v.w;
#pragma unroll
    for (int m = 1; m < 64; m <<= 1) ss += __shfl_xor(ss, m);
    float rinv = 1.0f / fmaxf(sqrtf(ss), 1e-8f);
    ushort4 o;
    o.x = f2bf(v.x * rinv);
    o.y = f2bf(v.y * rinv);
    o.z = f2bf(v.z * rinv);
    o.w = f2bf(v.w * rinv);
    ((ushort4*)(zn + (size_t)r * DDIM))[lane] = o;
    if (blockIdx.x < 32) rowacc[blockIdx.x * 256 + threadIdx.x] = 0.0f;
    if (blockIdx.x == 0 && threadIdx.x == 0) out[0] = 0.0f;
}

// ---------------- kernel 2: symmetric Gram + exp sums ----------------
// 64 row-groups of 128; triangle pairs I>=J: 2080 blocks. Block =
// S[I:128][J:128], K=256 in 4 steps of BK=64. 4 waves in 2x2; wave computes
// 64x64 = 4x4 fragments; acc (64 VGPR) is the only cross-loop state.
// Staging: width-16 global_load_lds, linear LDS dest, pre-swizzled global
// source (slot ^= row&7), same XOR on ds_read (verified R10: 0 conflicts).
// SINGLE 32 KB buffer -> 4 blocks/CU (16 waves/CU): cross-block overlap
// hides the per-step vmcnt(0) barrier drain (R10 failure: 64 KB dbuf ->
// 2 blocks/CU, 17.9% occupancy, MfmaUtil 10%, drains exposed).
// Row-sums -> rowacc[I rows]; col-sums (mirror, symmetry) -> rowacc[J rows];
// positives on local diag of I-J==32 blocks; self-diag masked when I==J.
__global__ __launch_bounds__(256, 4) void ntx_gram_kernel(
    const __hip_bfloat16* __restrict__ zn,
    float* __restrict__ rowacc,    // [TWO_N] atomic accumulation
    float* __restrict__ spos) {    // [TWO_N]
    // triangle decode over 64 groups
    const int b = blockIdx.x;
    int I = (int)((sqrtf(8.0f * b + 1.0f) - 1.0f) * 0.5f);
    while ((I + 1) * (I + 2) / 2 <= b) ++I;
    while (I * (I + 1) / 2 > b) --I;
    const int J = b - I * (I + 1) / 2;
    const bool sameIJ = (I == J);
    const bool posblk = (I - J) == 32;
    const int Ibase = I * 128, Jbase = J * 128;

    const int tid = threadIdx.x;
    const int w = tid >> 6, lane = tid & 63;
    const int wr = w >> 1, wc = w & 1;     // wave's 2x2 position
    const int lrow = lane & 15, lk = lane >> 4;

    const char* znb = (const char*)zn;     // zn row stride = 512 B

    __shared__ char lds[32768];            // A @ 0 (16KB), B @ 16384 (16KB)

    // staging geometry: 1 gload_lds = 1KB = 8 rows x 128B; lane -> (row, slot)
    const int sr = lane >> 3;              // row within 8-row slab
    const int ss = lane & 7;               // 16B slot within row

#define STAGE(kk)                                                             \
    do {                                                                      \
        _Pragma("unroll")                                                     \
        for (int p = 0; p < 4; ++p) {                                         \
            const int rb = w * 32 + p * 8;                                    \
            const int rr = rb + sr;                                           \
            const int so = ((ss ^ (rr & 7)) << 4);                            \
            const char* ga =                                                  \
                znb + (size_t)(Ibase + rr) * 512 + (kk) * 128 + so;           \
            const char* gb =                                                  \
                znb + (size_t)(Jbase + rr) * 512 + (kk) * 128 + so;           \
            __builtin_amdgcn_global_load_lds(                                 \
                (const AS1 void*)ga, (AS3 void*)(lds + rb * 128), 16, 0, 0);  \
            __builtin_amdgcn_global_load_lds(                                 \
                (const AS1 void*)gb, (AS3 void*)(lds + 16384 + rb * 128), 16, \
                0, 0);                                                        \
        }                                                                     \
    } while (0)

#define COMPUTE()                                                             \
    do {                                                                      \
        f32x4 a[4][2], bbf[4][2];                                             \
        _Pragma("unroll")                                                     \
        for (int rf = 0; rf < 4; ++rf) {                                      \
            const int r = wr * 64 + rf * 16 + lrow;                           \
            _Pragma("unroll")                                                 \
            for (int kb = 0; kb < 2; ++kb)                                    \
                a[rf][kb] = *(const f32x4*)(lds + r * 128 +                   \
                                            (((kb * 4 + lk) ^ (r & 7)) << 4));\
        }                                                                     \
        _Pragma("unroll")                                                     \
        for (int cf = 0; cf < 4; ++cf) {                                      \
            const int c = wc * 64 + cf * 16 + lrow;                           \
            _Pragma("unroll")                                                 \
            for (int kb = 0; kb < 2; ++kb)                                    \
                bbf[cf][kb] =                                                 \
                    *(const f32x4*)(lds + 16384 + c * 128 +                   \
                                    (((kb * 4 + lk) ^ (c & 7)) << 4));        \
        }                                                                     \
        _Pragma("unroll")                                                     \
        for (int kb = 0; kb < 2; ++kb) {                                      \
            _Pragma("unroll")                                                 \
            for (int rf = 0; rf < 4; ++rf)                                    \
                _Pragma("unroll")                                             \
                for (int cf = 0; cf < 4; ++cf)                                \
                    acc[rf][cf] = __builtin_amdgcn_mfma_f32_16x16x32_bf16(    \
                        __builtin_bit_cast(v8bf, a[rf][kb]),                  \
                        __builtin_bit_cast(v8bf, bbf[cf][kb]), acc[rf][cf],   \
                        0, 0, 0);                                             \
        }                                                                     \
    } while (0)

    f32x4 acc[4][4];
#pragma unroll
    for (int rf = 0; rf < 4; ++rf)
#pragma unroll
        for (int cf = 0; cf < 4; ++cf) acc[rf][cf] = (f32x4){0.f, 0.f, 0.f, 0.f};

#pragma unroll 1
    for (int k = 0; k < 4; ++k) {
        if (k > 0) __syncthreads();        // all reads of buffer done
        STAGE(k);
        __syncthreads();                   // vmcnt drained: tile k visible
        COMPUTE();
    }
#undef STAGE
#undef COMPUTE

    // ---------------- epilogue: exp, sums, spos, diag ----------------
    bool odg[4];
#pragma unroll
    for (int j = 0; j < 4; ++j) odg[j] = (lrow == lk * 4 + j);

    float rsum[4][4];
#pragma unroll
    for (int rf = 0; rf < 4; ++rf)
#pragma unroll
        for (int j = 0; j < 4; ++j) rsum[rf][j] = 0.0f;
    float csum[4] = {0.f, 0.f, 0.f, 0.f};

#pragma unroll
    for (int rf = 0; rf < 4; ++rf) {
#pragma unroll
        for (int cf = 0; cf < 4; ++cf) {
            const bool dfrag = (wr == wc) && (rf == cf);
#pragma unroll
            for (int j = 0; j < 4; ++j) {
                const float s = acc[rf][cf][j];
                const bool od = dfrag && odg[j];
                if (posblk && od) {
                    const int u = wr * 64 + rf * 16 + lk * 4 + j;
                    spos[Ibase + u] = s * INV_T;
                    spos[Jbase + u] = s * INV_T;
                }
                float e = EXP2F(s * SCALE);
                e = (sameIJ && od) ? 0.0f : e;
                rsum[rf][j] += e;
                csum[cf] += e;
            }
        }
    }

    // row-sums: reduce over the 16 col-lanes (bits 0..3 of lane)
#pragma unroll
    for (int rf = 0; rf < 4; ++rf) {
#pragma unroll
        for (int j = 0; j < 4; ++j) {
            float v = rsum[rf][j];
            v += __shfl_xor(v, 1);
            v += __shfl_xor(v, 2);
            v += __shfl_xor(v, 4);
            v += __shfl_xor(v, 8);
            if (lrow == 0)
                atomicAdd(&rowacc[Ibase + wr * 64 + rf * 16 + lk * 4 + j], v);
        }
    }
    // col-sums (mirror contribution): reduce over the 4 lk-groups
    if (!sameIJ) {
#pragma unroll
        for (int cf = 0; cf < 4; ++cf) {
            float v = csum[cf];
            v += __shfl_xor(v, 16);
            v += __shfl_xor(v, 32);
            if (lane < 16)
                atomicAdd(&rowacc[Jbase + wc * 64 + cf * 16 + lrow], v);
        }
    }
}

// ---------------- kernel 3: finalize ----------------
__global__ __launch_bounds__(256) void ntx_final_kernel(
    const float* __restrict__ rowacc, const float* __restrict__ spos,
    float* __restrict__ out) {
    const int tid = threadIdx.x;
    const int r = blockIdx.x * 256 + tid;
    float nll = logf(rowacc[r]) - spos[r];
    __shared__ float red[256];
    red[tid] = nll;
    __syncthreads();
    for (int s = 128; s > 0; s >>= 1) {
        if (tid < s) red[tid] += red[tid + s];
        __syncthreads();
    }
    if (tid == 0) atomicAdd(out, red[0] * (1.0f / (float)TWO_N));
}

extern "C" void kernel_launch(void* const* d_in, const int* in_sizes, int n_in,
                              void* d_out, int out_size, void* d_ws, size_t ws_size,
                              hipStream_t stream) {
    const float* zi = (const float*)d_in[0];
    const float* zj = (const float*)d_in[1];
    char* ws = (char*)d_ws;
    __hip_bfloat16* zn = (__hip_bfloat16*)ws;                          // 4 MB
    size_t off = (size_t)TWO_N * DDIM * 2;
    float* spos = (float*)(ws + off);                                  // 32 KB
    off += (size_t)TWO_N * 4;
    float* rowacc = (float*)(ws + off);                                // 32 KB
    float* out = (float*)d_out;

    ntx_norm_kernel<<<TWO_N / 4, 256, 0, stream>>>(zi, zj, zn, rowacc, out);
    ntx_gram_kernel<<<2080, 256, 0, stream>>>(zn, rowacc, spos);
    ntx_final_kernel<<<TWO_N / 256, 256, 0, stream>>>(rowacc, spos, out);
}

// Round 12
// 44.726 us; speedup vs baseline: 1.5470x; 1.3797x over previous
//
#include <hip/hip_runtime.h>
#include <hip/hip_bf16.h>

#define NHALF 4096
#define TWO_N 8192
#define DDIM 256
#define INV_T 10.0f
// 10 * log2(e): exp(10*s) = exp2(s * SCALE) where s is the raw cosine dot
#define SCALE 14.426950408889634f
// znB fragment-packed layout: byte(kb, row, lk) = kb*KBSTRIDE + row*64 + lk*16
// holding zn[row][kb*32 + lk*8 .. +7] as 16B of bf16.
#define KBSTRIDE ((size_t)TWO_N * 64)

typedef __bf16 v8bf __attribute__((ext_vector_type(8)));
typedef float f32x4 __attribute__((ext_vector_type(4)));

#if __has_builtin(__builtin_amdgcn_exp2f)
#define EXP2F(x) __builtin_amdgcn_exp2f(x)
#else
#define EXP2F(x) exp2f(x)
#endif

static __device__ __forceinline__ unsigned int f2bf(float x) {
    __hip_bfloat16 h = __float2bfloat16(x);
    return (unsigned int)*(unsigned short*)&h;
}

// ---- kernel 1: normalize rows -> fragment-packed bf16 znB; zero rowacc/out --
// one wave per row. lane holds elems 4l..4l+3; dest chunk: kb=l>>3,
// lk=(l>>1)&3, half=l&1 -> 8B store, 8x 64B segments per wave (4 MB total).
__global__ __launch_bounds__(256) void ntx_norm_kernel(
    const float* __restrict__ zi, const float* __restrict__ zj,
    char* __restrict__ znB, float* __restrict__ rowacc,
    float* __restrict__ out) {
    const int w = threadIdx.x >> 6;
    const int lane = threadIdx.x & 63;
    const int r = blockIdx.x * 4 + w;
    const float* src = (r < NHALF) ? (zi + (size_t)r * DDIM)
                                   : (zj + (size_t)(r - NHALF) * DDIM);
    float4 v = ((const float4*)src)[lane];
    float ss = v.x * v.x + v.y * v.y + v.z * v.z + v.w * v.w;
#pragma unroll
    for (int m = 1; m < 64; m <<= 1) ss += __shfl_xor(ss, m);
    float rinv = 1.0f / fmaxf(sqrtf(ss), 1e-8f);
    uint2 pk;
    pk.x = f2bf(v.x * rinv) | (f2bf(v.y * rinv) << 16);
    pk.y = f2bf(v.z * rinv) | (f2bf(v.w * rinv) << 16);
    char* dst = znB + (size_t)(lane >> 3) * KBSTRIDE + (size_t)r * 64 +
                ((lane >> 1) & 3) * 16 + (lane & 1) * 8;
    *(uint2*)dst = pk;
    if (blockIdx.x < 32) rowacc[blockIdx.x * 256 + threadIdx.x] = 0.0f;
    if (blockIdx.x == 0 && threadIdx.x == 0) out[0] = 0.0f;
}

// ---- kernel 2: symmetric Gram + exp sums — BARRIER-FREE, LDS-FREE ----------
// 128 row-tiles (64 rows). Wave task = (rt, g): tiles at cyclic distance
// d = 4g..4g+3 (ct = (rt-d) mod 128); g==15 & rt<64 adds the canonical d=64
// tile (positive pairs; writes spos for both halves). Every unordered tile
// pair covered exactly once (d + 128-d, one side in 1..63; d=64 canonical).
// d==0: self tile -> mask local diag, skip col-sums (row-sums == col-sums).
// Wave-private pipeline: af[4][8] (K=256, pinned) loaded once from znB
// (1-segment coalesced 1KB loads — R5's 16-segment gather failure is gone);
// B streamed per 16-col fragment, bfA/bfB alternating; acc per cf; exp
// epilogue interleaves with next cf's loads. NO __syncthreads (R6-R11: every
// barrier-coupled variant converged to ~47-52 us of exposed drain latency).
// 2048 waves = 512 blocks, balanced within 1 tile.
__global__ __launch_bounds__(256, 2) void ntx_gram_kernel(
    const char* __restrict__ znB,
    float* __restrict__ rowacc,    // [TWO_N] atomic accumulation
    float* __restrict__ spos) {    // [TWO_N]
    const int tid = threadIdx.x;
    const int w = tid >> 6, lane = tid & 63;
    const int task = blockIdx.x * 4 + w;
    const int rt = task >> 4, g = task & 15;
    const int rbase = rt * 64;
    const int lrow = lane & 15, lk = lane >> 4;
    const int nt = (g == 15 && rt < 64) ? 5 : 4;

    // A fragments for the full K=256: af[rf][kb]
    f32x4 af[4][8];
#pragma unroll
    for (int rf = 0; rf < 4; ++rf) {
        const char* ab =
            znB + (size_t)(rbase + rf * 16 + lrow) * 64 + lk * 16;
#pragma unroll
        for (int kb = 0; kb < 8; ++kb)
            af[rf][kb] = *(const f32x4*)(ab + kb * KBSTRIDE);
    }
#pragma unroll
    for (int rf = 0; rf < 4; ++rf)
#pragma unroll
        for (int kb = 0; kb < 8; ++kb)
            asm volatile("" : "+v"(af[rf][kb]));  // pin: no remat/sink

    bool odg[4];
#pragma unroll
    for (int j = 0; j < 4; ++j) odg[j] = (lrow == lk * 4 + j);

    float rowsum[4][4];
#pragma unroll
    for (int rf = 0; rf < 4; ++rf)
#pragma unroll
        for (int j = 0; j < 4; ++j) rowsum[rf][j] = 0.0f;

#define LOADB(bf, cf)                                                         \
    do {                                                                      \
        _Pragma("unroll")                                                     \
        for (int kb = 0; kb < 8; ++kb)                                        \
            bf[kb] = *(const f32x4*)(zcb + (cf) * 1024 + kb * KBSTRIDE);      \
    } while (0)

#define COMPUTE_EPI(bf, cf)                                                   \
    do {                                                                      \
        f32x4 acc[4];                                                         \
        _Pragma("unroll")                                                     \
        for (int rf = 0; rf < 4; ++rf) acc[rf] = (f32x4){0.f, 0.f, 0.f, 0.f}; \
        _Pragma("unroll")                                                     \
        for (int kb = 0; kb < 8; ++kb) {                                      \
            _Pragma("unroll")                                                 \
            for (int rf = 0; rf < 4; ++rf)                                    \
                acc[rf] = __builtin_amdgcn_mfma_f32_16x16x32_bf16(            \
                    __builtin_bit_cast(v8bf, af[rf][kb]),                     \
                    __builtin_bit_cast(v8bf, bf[kb]), acc[rf], 0, 0, 0);      \
        }                                                                     \
        float ce = 0.0f;                                                      \
        _Pragma("unroll")                                                     \
        for (int rf = 0; rf < 4; ++rf) {                                      \
            const bool dfrag = (rf == (cf));                                  \
            _Pragma("unroll")                                                 \
            for (int j = 0; j < 4; ++j) {                                     \
                const float sv = acc[rf][j];                                  \
                const bool od = dfrag && odg[j];                              \
                if (posb && od) {                                             \
                    const int u = rf * 16 + lk * 4 + j;                       \
                    spos[rbase + u] = sv * INV_T;                             \
                    spos[cb + u] = sv * INV_T;                                \
                }                                                             \
                float e = EXP2F(sv * SCALE);                                  \
                e = (self && od) ? 0.0f : e;                                  \
                rowsum[rf][j] += e;                                           \
                ce += e;                                                      \
            }                                                                 \
        }                                                                     \
        if (!self) {                                                          \
            ce += __shfl_xor(ce, 16);                                         \
            ce += __shfl_xor(ce, 32);                                         \
            if (lane < 16)                                                    \
                atomicAdd(&rowacc[cb + (cf) * 16 + lrow], ce);                \
        }                                                                     \
    } while (0)

#pragma unroll 1
    for (int s = 0; s < nt; ++s) {
        const int d = (s < 4) ? (g * 4 + s) : 64;
        const int ct = (rt - d + 128) & 127;
        const int cb = ct * 64;
        const bool self = (d == 0);
        const bool posb = (d == 64);
        const char* zcb = znB + (size_t)(cb + lrow) * 64 + lk * 16;
        f32x4 bfA[8], bfB[8];
        LOADB(bfA, 0);
        LOADB(bfB, 1);
        COMPUTE_EPI(bfA, 0);
        LOADB(bfA, 2);
        COMPUTE_EPI(bfB, 1);
        LOADB(bfB, 3);
        COMPUTE_EPI(bfA, 2);
        COMPUTE_EPI(bfB, 3);
    }
#undef LOADB
#undef COMPUTE_EPI

    // flush row-sums (reduce over the 16 col-lanes; bits 0..3 of lane)
#pragma unroll
    for (int rf = 0; rf < 4; ++rf) {
#pragma unroll
        for (int j = 0; j < 4; ++j) {
            float v = rowsum[rf][j];
            v += __shfl_xor(v, 1);
            v += __shfl_xor(v, 2);
            v += __shfl_xor(v, 4);
            v += __shfl_xor(v, 8);
            if (lrow == 0)
                atomicAdd(&rowacc[rbase + rf * 16 + lk * 4 + j], v);
        }
    }
}

// ---------------- kernel 3: finalize ----------------
__global__ __launch_bounds__(256) void ntx_final_kernel(
    const float* __restrict__ rowacc, const float* __restrict__ spos,
    float* __restrict__ out) {
    const int tid = threadIdx.x;
    const int r = blockIdx.x * 256 + tid;
    float nll = logf(rowacc[r]) - spos[r];
    __shared__ float red[256];
    red[tid] = nll;
    __syncthreads();
    for (int s = 128; s > 0; s >>= 1) {
        if (tid < s) red[tid] += red[tid + s];
        __syncthreads();
    }
    if (tid == 0) atomicAdd(out, red[0] * (1.0f / (float)TWO_N));
}

extern "C" void kernel_launch(void* const* d_in, const int* in_sizes, int n_in,
                              void* d_out, int out_size, void* d_ws, size_t ws_size,
                              hipStream_t stream) {
    const float* zi = (const float*)d_in[0];
    const float* zj = (const float*)d_in[1];
    char* ws = (char*)d_ws;
    char* znB = ws;                                                    // 4 MB
    size_t off = (size_t)TWO_N * DDIM * 2;
    float* spos = (float*)(ws + off);                                  // 32 KB
    off += (size_t)TWO_N * 4;
    float* rowacc = (float*)(ws + off);                                // 32 KB
    float* out = (float*)d_out;

    ntx_norm_kernel<<<TWO_N / 4, 256, 0, stream>>>(zi, zj, znB, rowacc, out);
    ntx_gram_kernel<<<512, 256, 0, stream>>>(znB, rowacc, spos);
    ntx_final_kernel<<<TWO_N / 256, 256, 0, stream>>>(rowacc, spos, out);
}